// Round 6
// baseline (144.411 us; speedup 1.0000x reference)
//
#include <hip/hip_runtime.h>
#include <stdint.h>

#define NROWS 2048
#define DDIM  9216
#define TILE  160
#define NT160 13                      // ceil(2048/160) worst case
#define NTRI160 91                    // 13*14/2 worst-case triangle tiles
#define KS    8                       // K-slices (one per XCD)
#define KSLEN 1152                    // DDIM/KS
#define BK    64                      // K-step per stage
#define KIT   18                      // KSLEN/BK

typedef unsigned short u16;
typedef __bf16 bf16x8 __attribute__((ext_vector_type(8)));
typedef float  f32x4  __attribute__((ext_vector_type(4)));

// ws layout: [0] int cnt, [4] float sq,
//            [256..) u16 nf[2048][9216]                      (37.75 MB)
//            [P_OFF..) float P[91][8][4][6400] partials      (74.5 MB max)
#define NF_OFF 256
#define P_OFF  37748992ull            // NF_OFF + 2048*9216*2 (16B aligned)

__device__ __forceinline__ u16 f2bf(float f) {
    uint32_t x = __float_as_uint(f);
    x += 0x7fffu + ((x >> 16) & 1u);          // round-to-nearest-even
    return (u16)(x >> 16);
}

__device__ __forceinline__ void gload16(const u16* g, u16* l) {
    __builtin_amdgcn_global_load_lds(
        (const __attribute__((address_space(1))) uint32_t*)g,
        (__attribute__((address_space(3))) uint32_t*)l, 16, 0, 0);
}

// ---------------- kernel 1: per-row stats + normalize + compact ----------------
__global__ __launch_bounds__(256) void stats_kernel(const float* __restrict__ wgt,
                                                    const float* __restrict__ mask,
                                                    u16* __restrict__ nf,
                                                    int* __restrict__ cnt) {
    int n = blockIdx.x;
    if (mask[n] == 0.0f) return;              // inactive filter: skip entirely
    int tid = threadIdx.x;
    const float4* row = (const float4*)(wgt + (size_t)n * DDIM);
    float4 v[9];
    float s = 0.f, ss = 0.f;
#pragma unroll
    for (int i = 0; i < 9; ++i) {
        v[i] = row[tid + 256 * i];
        s  += v[i].x + v[i].y + v[i].z + v[i].w;
        ss += v[i].x * v[i].x + v[i].y * v[i].y + v[i].z * v[i].z + v[i].w * v[i].w;
    }
#pragma unroll
    for (int o = 32; o > 0; o >>= 1) { s += __shfl_down(s, o); ss += __shfl_down(ss, o); }
    __shared__ float rs[4], rss[4];
    __shared__ float smean, sinv;
    __shared__ int   sidx;
    int w = tid >> 6, l = tid & 63;
    if (l == 0) { rs[w] = s; rss[w] = ss; }
    __syncthreads();
    if (tid == 0) {
        float S  = rs[0] + rs[1] + rs[2] + rs[3];
        float SS = rss[0] + rss[1] + rss[2] + rss[3];
        float mean = S / (float)DDIM;
        float var  = SS / (float)DDIM - mean * mean;
        float sd   = sqrtf(fmaxf(var, 0.f));
        if (sd == 0.f) sd = 1.f;              // reference: std==0 -> 1
        smean = mean; sinv = 1.f / sd;
        sidx = atomicAdd(cnt, 1);             // compacted slot (order irrelevant)
    }
    __syncthreads();
    float mean = smean, inv = sinv;
    u16* dst = nf + (size_t)sidx * DDIM;
#pragma unroll
    for (int i = 0; i < 9; ++i) {
        int e = (tid + 256 * i) * 4;
        uint32_t lo = (uint32_t)f2bf((v[i].x - mean) * inv) |
                      ((uint32_t)f2bf((v[i].y - mean) * inv) << 16);
        uint32_t hi = (uint32_t)f2bf((v[i].z - mean) * inv) |
                      ((uint32_t)f2bf((v[i].w - mean) * inv) << 16);
        uint2 u; u.x = lo; u.y = hi;
        *(uint2*)(dst + e) = u;
    }
}

// ---------------- kernel 2a: 160x160-tile partial GEMM, K-split by 8 ----------------
// TILE=160, nt=7 @ A~1024 -> 28 tri-tiles x 8 kslices = 224 active blocks
// <= 256 CUs: NO TAIL, 1 block/CU, kslice k -> XCD k pinning intact (28
// blocks per 32-CU XCD; per-XCD slab 1120x1152 bf16 = 2.58 MB, L2-resident).
// 4 waves, each owns an 80x80 quadrant (5x5 16x16 frags). 3-buffer 2-deep
// pipeline, 120 KB LDS, ONE barrier per K-step:
//   vmcnt(10) [own stage kt landed; kt+1 in flight] -> s_barrier
//   -> issue stage kt+2 [safe: barrier proves all waves done computing kt-1]
//   -> compute kt [other waves' kt staged: they drained before the barrier]
// Latency tolerance = 2 full steps (~1300 cy) > L3 round trip. Never drains
// vmcnt to 0 until the last step.
// XOR swizzle (verified R1-R5): global source col chunk (l&7)^(l>>3); read
// chunk ((kk*4+quad)^(m16&7)) -> bank-conflict-free ds_read_b128.
template<bool DIAG>
__device__ __forceinline__ void stage(const u16* pA, const u16* pB, int kt,
                                      u16* buf, int w) {
    const u16* a = pA + kt * BK;
    u16* Ad = buf + w * 2560;                 // 40 rows x 64 u16 per wave
#pragma unroll
    for (int i = 0; i < 5; ++i)
        gload16(a + (size_t)(8 * i) * DDIM, Ad + i * 512);
    if (!DIAG) {
        const u16* b = pB + kt * BK;
        u16* Bd = buf + 10240 + w * 2560;     // B half of the stage buffer
#pragma unroll
        for (int i = 0; i < 5; ++i)
            gload16(b + (size_t)(8 * i) * DDIM, Bd + i * 512);
    }
}

template<bool DIAG>
__device__ __forceinline__ void compute(const u16* buf, int wr, int wc,
                                        int m16, int quad, f32x4 acc[5][5]) {
    const u16* Ab = buf;
    const u16* Bb = DIAG ? buf : buf + 10240;
#pragma unroll
    for (int kk = 0; kk < 2; ++kk) {
        int sw = ((((kk << 2) | quad) ^ (m16 & 7)) << 3);
        bf16x8 af[5], bfr[5];
#pragma unroll
        for (int fm = 0; fm < 5; ++fm)
            af[fm] = *(const bf16x8*)&Ab[(wr * 80 + fm * 16 + m16) * 64 + sw];
#pragma unroll
        for (int fn = 0; fn < 5; ++fn)
            bfr[fn] = *(const bf16x8*)&Bb[(wc * 80 + fn * 16 + m16) * 64 + sw];
#pragma unroll
        for (int fm = 0; fm < 5; ++fm)
#pragma unroll
            for (int fn = 0; fn < 5; ++fn)
                acc[fm][fn] = __builtin_amdgcn_mfma_f32_16x16x32_bf16(
                    af[fm], bfr[fn], acc[fm][fn], 0, 0, 0);
    }
}

__device__ __forceinline__ void barrier_fenced() {
    asm volatile("" ::: "memory");
    __builtin_amdgcn_s_barrier();
    asm volatile("" ::: "memory");
}

// one K-step: wait own stage(kt), barrier, prefetch stage(kt+2), compute(kt)
template<bool DIAG, bool PRE, int VM>
__device__ __forceinline__ void kstep(const u16* pA, const u16* pB, int kt,
                                      u16* bufC, u16* bufT, int w, int wr, int wc,
                                      int m16, int quad, bool dead, f32x4 acc[5][5]) {
    __builtin_amdgcn_s_waitcnt(VM);
    barrier_fenced();
    if (PRE) stage<DIAG>(pA, pB, kt + 2, bufT, w);
    if (!dead) compute<DIAG>(bufC, wr, wc, m16, quad, acc);
}

template<bool DIAG>
__device__ __forceinline__ void kloop(const u16* pA, const u16* pB, u16* ls,
                                      int w, int wr, int wc, int m16, int quad,
                                      bool dead, f32x4 acc[5][5]) {
    u16* b0 = ls;                             // 40 KB per stage buffer
    u16* b1 = ls + 20480;
    u16* b2 = ls + 40960;
    constexpr int VMF = DIAG ? 0x0F75 : 0x0F7A;   // vmcnt(5) / vmcnt(10)
    stage<DIAG>(pA, pB, 0, b0, w);
    stage<DIAG>(pA, pB, 1, b1, w);
    for (int kt = 0; kt < KIT - 3; kt += 3) {
        kstep<DIAG, true, VMF>(pA, pB, kt,     b0, b2, w, wr, wc, m16, quad, dead, acc);
        kstep<DIAG, true, VMF>(pA, pB, kt + 1, b1, b0, w, wr, wc, m16, quad, dead, acc);
        kstep<DIAG, true, VMF>(pA, pB, kt + 2, b2, b1, w, wr, wc, m16, quad, dead, acc);
    }
    // steps 15,16,17: stage 17 issued at step 15; then drain
    kstep<DIAG, true,  VMF   >(pA, pB, KIT - 3, b0, b2, w, wr, wc, m16, quad, dead, acc);
    kstep<DIAG, false, VMF   >(pA, pB, KIT - 2, b1, b0, w, wr, wc, m16, quad, dead, acc);
    kstep<DIAG, false, 0x0F70>(pA, pB, KIT - 1, b2, b1, w, wr, wc, m16, quad, dead, acc);
}

__global__ __launch_bounds__(256) void gemm_kernel(const u16* __restrict__ nf,
                                                   const int* __restrict__ cnt,
                                                   float* __restrict__ P) {
    __shared__ u16 ls[61440];                 // 120 KB: 3 x (A 20KB + B 20KB)
    int A = *cnt;
    int nt = (A + TILE - 1) / TILE;
    int ntri = nt * (nt + 1) >> 1;
    int bid = blockIdx.x;
    int t = bid >> 3, k = bid & 7;            // k = bid%8 -> XCD k (round-robin)
    if (t >= ntri) return;                    // contiguous active prefix
    int tt = t, bi = 0, len = nt;
    while (tt >= len) { tt -= len; --len; ++bi; }
    int bj = bi + tt;                         // bi <= bj
    int r0 = bi * TILE, c0 = bj * TILE;
    int tid = threadIdx.x, l = tid & 63, w = tid >> 6;
    int quad = l >> 4, m16 = l & 15;
    int wr = w >> 1, wc = w & 1;
    int colsw = ((l & 7) ^ (l >> 3)) << 3;    // pre-swizzled global col chunk
    size_t kbase = (size_t)k * KSLEN + colsw;
    const u16* pA = nf + (size_t)(r0 + 40 * w + (l >> 3)) * DDIM + kbase;
    const u16* pB = nf + (size_t)(c0 + 40 * w + (l >> 3)) * DDIM + kbase;
    bool dead = (bi == bj) && (w == 2);       // rows 80-159 x cols 0-79: gi>gj always
    f32x4 acc[5][5] = {};
    if (bi == bj) kloop<true >(pA, pB, ls, w, wr, wc, m16, quad, dead, acc);
    else          kloop<false>(pA, pB, ls, w, wr, wc, m16, quad, dead, acc);
    // frag-major coalesced partial store: P[(t*8+k)*4 + w][frag][lane][reg]
    float* dst = P + ((size_t)(t * 8 + k) * 4 + w) * 6400;
#pragma unroll
    for (int fm = 0; fm < 5; ++fm)
#pragma unroll
        for (int fn = 0; fn < 5; ++fn)
            *(f32x4*)&dst[(fm * 5 + fn) * 256 + l * 4] = acc[fm][fn];
}

// ---------------- kernel 2b: reduce 8 k-partials, square, mask, sum ----------------
// 4 blocks per tile; block c owns wave-region w=c (1600 f32x4). Per k the
// block reads contiguous coalesced 25.6-KB spans; 8 loads in flight/thread.
__global__ __launch_bounds__(256) void reduce_kernel(const float* __restrict__ P,
                                                     const int* __restrict__ cnt,
                                                     float* __restrict__ sq) {
    int A = *cnt;
    int nt = (A + TILE - 1) / TILE;
    int ntri = nt * (nt + 1) >> 1;
    int t = blockIdx.x >> 2, c = blockIdx.x & 3;
    if (t >= ntri) return;
    int tt = t, bi = 0, len = nt;             // SAME nt-triangle mapping as gemm
    while (tt >= len) { tt -= len; --len; ++bi; }
    int bj = bi + tt;
    int r0 = bi * TILE, c0 = bj * TILE;
    int tid = threadIdx.x, l = tid & 63;
    const float* base = P + (size_t)t * 204800 + (size_t)c * 6400;
    float local = 0.f;
#pragma unroll
    for (int mm = 0; mm < 7; ++mm) {
        int idx = mm * 256 + tid;             // f32x4 index within region [0,1600)
        if (idx < 1600) {
            const float* p0 = base + (size_t)idx * 4;
            f32x4 s = *(const f32x4*)p0;
#pragma unroll
            for (int kk = 1; kk < 8; ++kk) s += *(const f32x4*)(p0 + (size_t)kk * 25600);
            int f = idx >> 6, ln = idx & 63;
            int i = ((c >> 1) * 80) + (f / 5) * 16 + ((ln >> 4) << 2);
            int j = ((c & 1) * 80) + (f % 5) * 16 + (ln & 15);
            int gj = c0 + j;
            if (gj < A) {
#pragma unroll
                for (int r = 0; r < 4; ++r) {
                    int gi = r0 + i + r;
                    if (gi < gj) local += s[r] * s[r];
                }
            }
        }
    }
#pragma unroll
    for (int o = 32; o > 0; o >>= 1) local += __shfl_down(local, o);
    if (l == 0) atomicAdd(sq, local);         // 4 atomics per active block
}

// ---------------- kernel 3: finalize ----------------
__global__ void final_kernel(const int* __restrict__ cnt, const float* __restrict__ sq,
                             float* __restrict__ out) {
    long long A = *cnt;
    long long na = A * (A - 1) / 2;           // sum of strict-upper mask products
    double loss = 0.0;
    if (na > 0) loss = (double)(*sq) / ((double)DDIM * (double)DDIM) / (double)na;
    out[0] = (float)loss;
}

extern "C" void kernel_launch(void* const* d_in, const int* in_sizes, int n_in,
                              void* d_out, int out_size, void* d_ws, size_t ws_size,
                              hipStream_t stream) {
    (void)in_sizes; (void)n_in; (void)out_size; (void)ws_size;
    const float* wgt  = (const float*)d_in[0];
    const float* mask = (const float*)d_in[1];
    float* out = (float*)d_out;
    char*  ws  = (char*)d_ws;

    int*   cnt = (int*)ws;
    float* sq  = (float*)(ws + 4);
    u16*   nf  = (u16*)(ws + NF_OFF);
    float* P   = (float*)(ws + P_OFF);

    hipMemsetAsync(ws, 0, 256, stream);
    stats_kernel<<<NROWS, 256, 0, stream>>>(wgt, mask, nf, cnt);
    gemm_kernel<<<NTRI160 * KS, 256, 0, stream>>>(nf, cnt, P);
    reduce_kernel<<<NTRI160 * 4, 256, 0, stream>>>(P, cnt, sq);
    final_kernel<<<1, 1, 0, stream>>>(cnt, sq, out);
}